// Round 1
// 97.210 us; speedup vs baseline: 1.0108x; 1.0108x over previous
//
#include <hip/hip_runtime.h>
#include <math.h>

#define BIGV 10000000000.0f
#define WA   0.096f
#define ABSENT 16000   // sentinel: "no seed" (real max d2 = 3*63^2 = 11907)

typedef short short2v __attribute__((ext_vector_type(2)));
typedef short short8v __attribute__((ext_vector_type(8)));

__device__ __forceinline__ short2v pack2(int a, int b) {
    short2v r; r.x = (short)a; r.y = (short)b; return r;
}

// nearest-seed distance^2 (integer, exact) along x from a 64-bit seed mask.
__device__ __forceinline__ short seed_d2_i16(unsigned long long mask, int i) {
    const unsigned long long mr = mask >> i;          // seeds at j >= i
    const unsigned long long ml = mask << (63 - i);   // seeds at j <= i
    const int dr = mr ? __builtin_ctzll(mr) : 127;
    const int dl = ml ? __builtin_clzll(ml) : 127;
    const int d  = dr < dl ? dr : dl;
    return (short)(d > 63 ? ABSENT : d * d);
}

// Shared scan core: min-plus over 64 j for 4 output rows (i0..i0+3), 3 labels.
// LDS layout is TRANSPOSED + swizzled: value (L, x, j) lives at
//   smb[L*4096 + x*64 + ((j>>3 ^ (x&7))<<3) + (j&7)]
// so each lane (x) reads 8 consecutive j per ds_read_b128; the XOR swizzle puts
// the wave's 1KB read at the 8-cycle LDS floor (8 lanes per 4-bank group).
// d2 packs: rows{i0+2,i0+3} at j == rows{i0,i0+1} at j-2 -> 2-deep delay reg,
// halving the SALU pack chain.
struct Acc { short2v A0, A1, B0, B1, C0, C1; };

__device__ __forceinline__ Acc scan64(const short* __restrict__ smb,
                                      int lane, int i0) {
    Acc m;
    m.A0 = (short2v){32767, 32767};
    m.A1 = m.A0; m.B0 = m.A0; m.B1 = m.A0; m.C0 = m.A0; m.C1 = m.A0;

    const int xr = lane & 7;
    short2v d2m2 = pack2((i0 + 2) * (i0 + 2), (i0 + 3) * (i0 + 3)); // formula(-2)
    short2v d2m1 = pack2((i0 + 1) * (i0 + 1), (i0 + 2) * (i0 + 2)); // formula(-1)

#pragma unroll
    for (int c = 0; c < 8; ++c) {
        const int base = lane * 64 + ((c ^ xr) << 3);
        const short8v a0 = *(const short8v*)(smb + base);
        const short8v a1 = *(const short8v*)(smb + 4096 + base);
        const short8v a2 = *(const short8v*)(smb + 8192 + base);
#pragma unroll
        for (int k = 0; k < 8; ++k) {
            const int j  = c * 8 + k;
            const int dz = i0 - j;
            const short2v cur = pack2(dz * dz, (dz + 1) * (dz + 1)); // rows {i0,i0+1}
            const short2v dP  = d2m2;                                 // rows {i0+2,i0+3}
            const short2v a0p = {a0[k], a0[k]};
            const short2v a1p = {a1[k], a1[k]};
            const short2v a2p = {a2[k], a2[k]};
            m.A0 = __builtin_elementwise_min(m.A0, (short2v)(a0p + cur));
            m.A1 = __builtin_elementwise_min(m.A1, (short2v)(a0p + dP));
            m.B0 = __builtin_elementwise_min(m.B0, (short2v)(a1p + cur));
            m.B1 = __builtin_elementwise_min(m.B1, (short2v)(a1p + dP));
            m.C0 = __builtin_elementwise_min(m.C0, (short2v)(a2p + cur));
            m.C1 = __builtin_elementwise_min(m.C1, (short2v)(a2p + dP));
            d2m2 = d2m1; d2m1 = cur;
        }
    }
    return m;
}

// Kernel A: x-pass (ballot) + z-pass, integer d2 domain, all 3 labels.
// Grid (y=64, b=2, zq=4), 256 threads. D layout: [b*3+L][z][y][x] uint16.
// Also initializes out[0] = 1e-5 (stream order: A completes before B's atomics).
__global__ __launch_bounds__(256) void pass_xz_kernel(const int* __restrict__ lab,
                                                      unsigned short* __restrict__ D,
                                                      float* __restrict__ out) {
    if (blockIdx.x == 0 && blockIdx.y == 0 && blockIdx.z == 0 && threadIdx.x == 0)
        out[0] = 1e-5f;

    const int ys = blockIdx.x, b = blockIdx.y, zq = blockIdx.z;
    const int lane = threadIdx.x & 63;
    const int wv   = threadIdx.x >> 6;
    const int xr   = lane & 7;

    __shared__ short sm[3][64][64];                  // transposed [L][x][z-swz], 24 KB
    short* smb = &sm[0][0][0];

    const int* lp = lab + b * 262144 + ys * 64;
    // stage: 2 chunks of 8 z per wave; accumulate short8 in regs, one b128 write per label
#pragma unroll
    for (int zz = 0; zz < 2; ++zz) {
        const int zb = 2 * wv + zz;
        short8v s0, s1, s2;
#pragma unroll
        for (int k = 0; k < 8; ++k) {
            const int z  = zb * 8 + k;
            const int lv = lp[z * 4096 + lane];
            s0[k] = seed_d2_i16(__ballot(lv == 0), lane);
            s1[k] = seed_d2_i16(__ballot(lv == 1), lane);
            s2[k] = seed_d2_i16(__ballot(lv == 2), lane);
        }
        const int base = lane * 64 + ((zb ^ xr) << 3);
        *(short8v*)(smb + base)        = s0;
        *(short8v*)(smb + 4096 + base) = s1;
        *(short8v*)(smb + 8192 + base) = s2;
    }
    __syncthreads();

    const int i0 = zq * 16 + wv * 4;                 // 4 output-z rows per wave
    const Acc m = scan64(smb, lane, i0);

    // coalesced 16-bit stores (lanes = consecutive x), layout unchanged
    unsigned short* Dp = D + b * 3 * 262144 + ys * 64 + lane;
    const int r0 = i0 * 4096;
    Dp[r0]                       = (unsigned short)m.A0.x;
    Dp[r0 + 4096]                = (unsigned short)m.A0.y;
    Dp[r0 + 2 * 4096]            = (unsigned short)m.A1.x;
    Dp[r0 + 3 * 4096]            = (unsigned short)m.A1.y;
    Dp[262144 + r0]              = (unsigned short)m.B0.x;
    Dp[262144 + r0 + 4096]       = (unsigned short)m.B0.y;
    Dp[262144 + r0 + 2 * 4096]   = (unsigned short)m.B1.x;
    Dp[262144 + r0 + 3 * 4096]   = (unsigned short)m.B1.y;
    Dp[524288 + r0]              = (unsigned short)m.C0.x;
    Dp[524288 + r0 + 4096]       = (unsigned short)m.C0.y;
    Dp[524288 + r0 + 2 * 4096]   = (unsigned short)m.C1.x;
    Dp[524288 + r0 + 3 * 4096]   = (unsigned short)m.C1.y;
}

// Kernel B: y-pass (integer) + penalty epilogue + reduction, per (b, z) slice.
// Grid (z=64, b=2, yq=4), 256 threads.
__global__ __launch_bounds__(256) void pass_y_kernel(const float* __restrict__ x,
                                                     const int* __restrict__ lab,
                                                     const unsigned short* __restrict__ D,
                                                     float* __restrict__ out) {
    const int z = blockIdx.x, b = blockIdx.y, yq = blockIdx.z;
    const int lane = threadIdx.x & 63;
    const int wv   = threadIdx.x >> 6;

    __shared__ short sm[3][64][64];                  // transposed [L][x][y-swz], 24 KB
    short* smb = &sm[0][0][0];

    // staging with transpose: coalesced uint4 global loads (8 x at fixed y),
    // scattered swizzled u16 LDS writes into [x][y] layout.
    {
        const unsigned short* Dp = D + b * 3 * 262144 + z * 4096;
#pragma unroll
        for (int tt = 0; tt < 2; ++tt) {
            const int t  = (int)threadIdx.x + tt * 256;  // 512 uint4 per plane
            const int y  = t >> 3;
            const int x0 = (t & 7) << 3;
            const int yc = (y >> 3);
            const int yl = (y & 7);
#pragma unroll
            for (int L = 0; L < 3; ++L) {
                const uint4 v = ((const uint4*)(Dp + L * 262144))[t];
                const unsigned int ww[4] = {v.x, v.y, v.z, v.w};
#pragma unroll
                for (int k = 0; k < 8; ++k) {         // (x0+k)&7 == k
                    const short e = (short)(ww[k >> 1] >> ((k & 1) << 4));
                    smb[L * 4096 + (x0 + k) * 64 + ((yc ^ k) << 3) + yl] = e;
                }
            }
        }
    }

    // Prefetch epilogue inputs before the compute loop (hide global latency).
    const int i0 = yq * 16 + wv * 4;                 // 4 output-y rows per wave
    int   lv[4];
    float x1[4], x2[4];
#pragma unroll
    for (int ii = 0; ii < 4; ++ii) {
        const int off = z * 4096 + (i0 + ii) * 64 + lane;
        lv[ii] = lab[b * 262144 + off];
        x1[ii] = x[(b * 3 + 1) * 262144 + off];
        x2[ii] = x[(b * 3 + 2) * 262144 + off];
    }
    __syncthreads();

    const Acc m = scan64(smb, lane, i0);

    const int g0[4] = {m.A0.x, m.A0.y, m.A1.x, m.A1.y};
    const int g1[4] = {m.B0.x, m.B0.y, m.B1.x, m.B1.y};
    const int g2[4] = {m.C0.x, m.C0.y, m.C1.x, m.C1.y};

    float part = 0.0f;
#pragma unroll
    for (int ii = 0; ii < 4; ++ii) {
        const int e0 = (lv[ii] == 0) ? (1 << 20) : g0[ii];
        const int e1 = (lv[ii] == 1) ? (1 << 20) : g1[ii];
        const int e2 = (lv[ii] == 2) ? (1 << 20) : g2[ii];
        const int dm = min(e0, min(e1, e2));
        const float d2f = (dm >= ABSENT) ? BIGV : (float)dm * (WA * WA);
        const float dt  = sqrtf(d2f) + 1.0f;
        const float t1  = (lv[ii] == 1) ? (1.0f - x1[ii]) : x1[ii];
        const float t2  = (lv[ii] == 2) ? (1.0f - x2[ii]) : x2[ii];
        part += (t1 + t2) * dt;
    }

#pragma unroll
    for (int o = 32; o; o >>= 1) part += __shfl_down(part, o);
    if (lane == 0)
        atomicAdd(out, part * (1.0f / 1048576.0f));
}

extern "C" void kernel_launch(void* const* d_in, const int* in_sizes, int n_in,
                              void* d_out, int out_size, void* d_ws, size_t ws_size,
                              hipStream_t stream) {
    const float* x = (const float*)d_in[0];   // (2,3,64,64,64) fp32
    const int*   y = (const int*)d_in[1];     // (2,1,64,64,64) int32
    unsigned short* D = (unsigned short*)d_ws; // 6 * 262144 uint16 = 3 MB
    float* out = (float*)d_out;

    pass_xz_kernel<<<dim3(64, 2, 4), 256, 0, stream>>>(y, D, out);
    pass_y_kernel<<<dim3(64, 2, 4), 256, 0, stream>>>(x, y, D, out);
}